// Round 12
// baseline (246.667 us; speedup 1.0000x reference)
//
#include <hip/hip_runtime.h>
#include <cstdint>
#include <cstddef>

#define NN 250000   // nodes
#define FF 256      // channels
#define GG 4096     // graphs
#define TT 6        // processing steps
#define GPB 16      // graphs per block in steps_kernel
#define SBLK (GG / GPB)   // 256 blocks

typedef _Float16 half8_t __attribute__((ext_vector_type(8)));
typedef _Float16 half4_t __attribute__((ext_vector_type(4)));
typedef _Float16 half2_t __attribute__((ext_vector_type(2)));
typedef float f32x4 __attribute__((ext_vector_type(4)));

__device__ __forceinline__ float fdot2f(half2_t a, half2_t b, float c) {
#if __has_builtin(__builtin_amdgcn_fdot2)
  return __builtin_amdgcn_fdot2(a, b, c, false);
#else
  return c + (float)a[0] * (float)b[0] + (float)a[1] * (float)b[1];
#endif
}

__device__ __forceinline__ float dot8(half8_t x, half8_t q) {
  float d = fdot2f((half2_t){x[0], x[1]}, (half2_t){q[0], q[1]}, 0.f);
  d = fdot2f((half2_t){x[2], x[3]}, (half2_t){q[2], q[3]}, d);
  d = fdot2f((half2_t){x[4], x[5]}, (half2_t){q[4], q[5]}, d);
  d = fdot2f((half2_t){x[6], x[7]}, (half2_t){q[6], q[7]}, d);
  return d;
}

// ---------------- t=0: fused prep + bias-LSTM + f32 sweep + x16 mirror ----------------
// Builds fragment-major w16f: element (n,k) -> w16f[((n>>4)*16 + (k>>5))*512 +
// ((k>>3)&3)*128 + (n&15)*8 + (k&7)] so a wave's B-frag load is one 1 KB burst.
__global__ __launch_bounds__(256) void attn0_kernel(
    const float* __restrict__ x32, const int* __restrict__ batch,
    const float* __restrict__ Wih, const float* __restrict__ Whh,
    const float* __restrict__ bih, const float* __restrict__ bhh,
    _Float16* __restrict__ w16f, int* __restrict__ starts,
    _Float16* __restrict__ x16w, _Float16* __restrict__ q16out) {
  int g = blockIdx.x, tid = threadIdx.x, lane = tid & 63, w = tid >> 6;
  __shared__ int sgs[2];
  __shared__ __align__(16) float h_sh[FF];
  __shared__ __align__(16) float rw[4][FF];
  __shared__ float mw[4], sw[4];

  if (tid < 2) {
    int target = g + tid;
    int lo = 0;
    if (target >= GG) lo = NN;
    else {
      int hi = NN;
      while (lo < hi) {
        int mid = (lo + hi) >> 1;
        if (batch[mid] < target) lo = mid + 1; else hi = mid;
      }
    }
    sgs[tid] = lo;
    starts[g + tid] = lo;
  }

  // w16f prep: blocks 0..511 x 1024 elements = 524288 exactly.
  if (g < 512) {
#pragma unroll
    for (int e = 0; e < 4; ++e) {
      int idx = g * 1024 + e * 256 + tid;
      int n = idx >> 9, k = idx & 511;
      float v = Wih[(size_t)n * 512 + k];
      if (k < FF) v += Whh[(size_t)n * FF + k];
      int dest = ((n >> 4) * 16 + (k >> 5)) * 512 + ((k >> 3) & 3) * 128 +
                 (n & 15) * 8 + (k & 7);
      w16f[dest] = (_Float16)v;
    }
  }

  // t0 LSTM: gates = bias only (q_star = h = c = 0); identical for all graphs
  float bi = bih[tid] + bhh[tid];
  float bg = bih[tid + 512] + bhh[tid + 512];
  float bo = bih[tid + 768] + bhh[tid + 768];
  float si0 = 1.f / (1.f + __expf(-bi));
  float so0 = 1.f / (1.f + __expf(-bo));
  float cv0 = si0 * tanhf(bg);
  float hv0 = so0 * tanhf(cv0);
  q16out[(size_t)g * 512 + tid] = (_Float16)hv0;  // h half for t1 gemm
  h_sh[tid] = hv0;
  __syncthreads();

  f32x4 qv = *(const f32x4*)&h_sh[4 * lane];
  int s0 = sgs[0], cnt = sgs[1] - sgs[0];

  float m = -INFINITY, ssum = 0.f;
  f32x4 racc = {0.f, 0.f, 0.f, 0.f};
  for (int i0 = w * 4; i0 < cnt; i0 += 16) {
    f32x4 xv[4];
    float d[4];
    bool vld[4];
#pragma unroll
    for (int j = 0; j < 4; ++j) {              // 4 x 1 KB NT loads in flight
      int idx = i0 + j;
      vld[j] = idx < cnt;
      int node = vld[j] ? idx : cnt - 1;
      xv[j] = __builtin_nontemporal_load(
          (const f32x4*)(x32 + (size_t)(s0 + node) * FF + 4 * lane));
    }
#pragma unroll
    for (int j = 0; j < 4; ++j) {              // x16 mirror (dup-clamped ok)
      half4_t hx;
      hx[0] = (_Float16)xv[j][0]; hx[1] = (_Float16)xv[j][1];
      hx[2] = (_Float16)xv[j][2]; hx[3] = (_Float16)xv[j][3];
      int node = vld[j] ? (i0 + j) : cnt - 1;
      *(half4_t*)(x16w + (size_t)(s0 + node) * FF + 4 * lane) = hx;
    }
#pragma unroll
    for (int j = 0; j < 4; ++j)
      d[j] = xv[j][0] * qv[0] + xv[j][1] * qv[1] + xv[j][2] * qv[2] + xv[j][3] * qv[3];
#pragma unroll
    for (int off = 32; off; off >>= 1)
#pragma unroll
      for (int j = 0; j < 4; ++j) d[j] += __shfl_xor(d[j], off);
#pragma unroll
    for (int j = 0; j < 4; ++j) if (!vld[j]) d[j] = -INFINITY;
    float gm = fmaxf(fmaxf(d[0], d[1]), fmaxf(d[2], d[3]));
    if (gm > m) {                              // wave-uniform
      float sc = __expf(m - gm);
      ssum *= sc; racc *= sc;
      m = gm;
    }
#pragma unroll
    for (int j = 0; j < 4; ++j) {
      float p = __expf(d[j] - m);              // invalid: exp(-inf)=0
      ssum += p;
      racc += p * xv[j];
    }
  }

  if (lane == 0) { mw[w] = m; sw[w] = ssum; }
  *(f32x4*)&rw[w][4 * lane] = racc;
  __syncthreads();
  float M = fmaxf(fmaxf(mw[0], mw[1]), fmaxf(mw[2], mw[3]));
  float e0 = (mw[0] == -INFINITY) ? 0.f : __expf(mw[0] - M);
  float e1 = (mw[1] == -INFINITY) ? 0.f : __expf(mw[1] - M);
  float e2 = (mw[2] == -INFINITY) ? 0.f : __expf(mw[2] - M);
  float e3 = (mw[3] == -INFINITY) ? 0.f : __expf(mw[3] - M);
  float denom = sw[0] * e0 + sw[1] * e1 + sw[2] * e2 + sw[3] * e3;
  float rs = rw[0][tid] * e0 + rw[1][tid] * e1 + rw[2][tid] * e2 + rw[3][tid] * e3;
  float r = rs / (denom + 1e-16f);
  if (cnt == 0) r = 0.f;
  q16out[(size_t)g * 512 + FF + tid] = (_Float16)r;  // r half for t1 gemm
}

// ---------------- t=1..5: all remaining steps, 16 waves/block ----------------
// 256 blocks x 1024 threads (16 waves = 4/SIMD; R11's 2/SIMD still showed
// VALUBusy 34% / occupancy 21% -> latency exposure remains the limiter).
// Block owns graphs [b*16, b*16+16); q_star (f16) + c (f32) live in LDS.
// gemm: wave owns 16 f-cols x 4 gates. attn: wave w owns graph w exactly.
__global__ __launch_bounds__(1024, 1) void steps_kernel(
    const _Float16* __restrict__ x16, const _Float16* __restrict__ w16f,
    const _Float16* __restrict__ q16a, const int* __restrict__ starts,
    const float* __restrict__ bih, const float* __restrict__ bhh,
    float* __restrict__ qstar) {
  int tid = threadIdx.x, lane = tid & 63, w = tid >> 6;   // w in 0..15
  int lr = lane & 15, kq = lane >> 4;     // gemm quarter coords
  int sl = lane & 31, hf = lane >> 5;     // attn half coords
  int g0 = blockIdx.x * GPB;

  __shared__ _Float16 qs[GPB][520];       // q_star rows (520 = 512 + 8 pad)
  __shared__ float cst[GPB][256];         // LSTM cell state
  __shared__ int sgs[GPB + 1];

  // ---- init: starts, q_star from attn0, c0 (bias-only) ----
  if (tid <= GPB) sgs[tid] = starts[g0 + tid];
  {                                       // 16 rows x 64 half8 = 1024 chunks
    int i = tid >> 6, c8 = tid & 63;
    *(half8_t*)&qs[i][c8 * 8] =
        *(const half8_t*)(q16a + (size_t)(g0 + i) * 512 + c8 * 8);
  }
  {
    int f = tid & 255;
    float bi = bih[f] + bhh[f];
    float bg = bih[f + 512] + bhh[f + 512];
    float si0 = 1.f / (1.f + __expf(-bi));
    float cv0 = si0 * tanhf(bg);
    for (int i = tid >> 8; i < GPB; i += 4) cst[i][f] = cv0;
  }
  // pointwise biases: wave w owns f-cols [w*16, w*16+16)
  int f = w * 16 + lr;
  float bi_ = bih[f] + bhh[f];
  float bf_ = bih[f + 256] + bhh[f + 256];
  float bg_ = bih[f + 512] + bhh[f + 512];
  float bo_ = bih[f + 768] + bhh[f + 768];
  __syncthreads();

  for (int t = 1; t < TT; ++t) {
    bool last = (t == TT - 1);

    // ---- gemm: 16 graphs x 16 f-cols x 4 gates, K = 512 ----
    f32x4 acc[4];                         // [gate]
#pragma unroll
    for (int gt = 0; gt < 4; ++gt) acc[gt] = (f32x4){0.f, 0.f, 0.f, 0.f};

#pragma unroll 4
    for (int ks = 0; ks < 16; ++ks) {
      int kk = ks * 32 + kq * 8;
      half8_t a = *(const half8_t*)&qs[lr][kk];   // A[graph=lr][k]
#pragma unroll
      for (int gt = 0; gt < 4; ++gt) {
        int nf = gt * 16 + w;                     // W row-tile index
        half8_t b = *(const half8_t*)(
            w16f + ((size_t)nf * 16 + ks) * 512 + lane * 8);
        acc[gt] = __builtin_amdgcn_mfma_f32_16x16x32_f16(a, b, acc[gt], 0, 0, 0);
      }
    }
    __syncthreads();   // all waves done reading qs before h overwrite

    // ---- LSTM pointwise: lane holds all 4 gates of (graph kq*4+r, f) ----
#pragma unroll
    for (int r = 0; r < 4; ++r) {
      int gl = kq * 4 + r;
      float ig = acc[0][r] + bi_;
      float fg = acc[1][r] + bf_;
      float gv = acc[2][r] + bg_;
      float og = acc[3][r] + bo_;
      float si = 1.f / (1.f + __expf(-ig));
      float sf = 1.f / (1.f + __expf(-fg));
      float so = 1.f / (1.f + __expf(-og));
      float cv = sf * cst[gl][f] + si * tanhf(gv);
      float hv = so * tanhf(cv);
      cst[gl][f] = cv;
      qs[gl][f] = (_Float16)hv;
      if (last) qstar[(size_t)(g0 + gl) * 512 + f] = hv;
    }
    __syncthreads();   // full h rows visible before attn reads them

    // ---- attention: wave w owns graph w ----
    {
      int ii = w;
      int s0 = sgs[ii];
      int cnt = sgs[ii + 1] - s0;
      half8_t qh = *(const half8_t*)&qs[ii][sl * 8];

      float m = -INFINITY, ssum = 0.f;
      float racc[8];
#pragma unroll
      for (int e = 0; e < 8; ++e) racc[e] = 0.f;

      for (int i0 = 0; i0 < cnt; i0 += 16) {     // 16 nodes/iter/wave
        half8_t hx[8];
        float d[8];
        bool vld[8];
#pragma unroll
        for (int j = 0; j < 8; ++j) {            // 8 x 1 KB loads in flight
          int idx = i0 + j * 2 + hf;
          vld[j] = idx < cnt;
          int node = vld[j] ? idx : cnt - 1;
          hx[j] = *(const half8_t*)(x16 + (size_t)(s0 + node) * FF + sl * 8);
        }
#pragma unroll
        for (int j = 0; j < 8; ++j) d[j] = dot8(hx[j], qh);
#pragma unroll
        for (int off = 1; off <= 16; off <<= 1)  // 8 interleaved 32-lane trees
#pragma unroll
          for (int j = 0; j < 8; ++j) d[j] += __shfl_xor(d[j], off);
#pragma unroll
        for (int j = 0; j < 8; ++j) if (!vld[j]) d[j] = -INFINITY;
        float gm = -INFINITY;
#pragma unroll
        for (int j = 0; j < 8; ++j) {
          float dother = __shfl_xor(d[j], 32);
          gm = fmaxf(gm, fmaxf(d[j], dother));   // uniform across wave
        }
        if (gm > m) {                            // one rescale per 16 nodes
          float sc = __expf(m - gm);
          ssum *= sc;
#pragma unroll
          for (int e = 0; e < 8; ++e) racc[e] *= sc;
          m = gm;
        }
#pragma unroll
        for (int j = 0; j < 8; ++j) {
          float p = __expf(d[j] - m);            // invalid: exp(-inf)=0
          ssum += p;
#pragma unroll
          for (int e = 0; e < 8; ++e) racc[e] += p * (float)hx[j][e];
        }
      }

      // combine the two 32-lane halves; lane sl holds channels sl*8..+8
      ssum += __shfl_xor(ssum, 32);
#pragma unroll
      for (int e = 0; e < 8; ++e) racc[e] += __shfl_xor(racc[e], 32);
      float inv = 1.0f / (ssum + 1e-16f);

      if (hf == 0) {
        half8_t rh;
        float rv[8];
#pragma unroll
        for (int e = 0; e < 8; ++e) {
          rv[e] = (cnt == 0) ? 0.f : racc[e] * inv;
          rh[e] = (_Float16)rv[e];
        }
        *(half8_t*)&qs[ii][256 + sl * 8] = rh;   // r half for next gemm
        if (last) {
          f32x4 lo = {rv[0], rv[1], rv[2], rv[3]};
          f32x4 hi = {rv[4], rv[5], rv[6], rv[7]};
          *(f32x4*)(qstar + (size_t)(g0 + ii) * 512 + 256 + sl * 8) = lo;
          *(f32x4*)(qstar + (size_t)(g0 + ii) * 512 + 260 + sl * 8) = hi;
        }
      }
    }
    __syncthreads();   // r halves written before next step's gemm reads qs
  }
}

// ---------------- launcher ----------------
extern "C" void kernel_launch(void* const* d_in, const int* in_sizes, int n_in,
                              void* d_out, int out_size, void* d_ws, size_t ws_size,
                              hipStream_t stream) {
  const float* x   = (const float*)d_in[0];
  const int* batch = (const int*)d_in[1];
  // d_in[2] = size (4096), hard-coded
  const float* Wih = (const float*)d_in[3];
  const float* Whh = (const float*)d_in[4];
  const float* bih = (const float*)d_in[5];
  const float* bhh = (const float*)d_in[6];
  float* qstar = (float*)d_out;  // [GG, 512]; steps_kernel t=5 writes it

  uint8_t* p = (uint8_t*)d_ws;
  auto alloc = [&](size_t bytes) {
    uint8_t* q = p;
    p += (bytes + 255) & ~(size_t)255;
    return q;
  };
  _Float16* q16a = (_Float16*)alloc((size_t)GG * 2 * FF * 2);     // 4 MB
  _Float16* w16f = (_Float16*)alloc((size_t)4 * FF * 2 * FF * 2); // 1 MB
  int* starts    = (int*)alloc((size_t)(GG + 1) * 4);
  _Float16* x16  = (_Float16*)alloc((size_t)NN * FF * 2);         // 128 MB

  // t = 0: prep (starts + swizzled W) + bias-only LSTM + f32 sweep + x16 mirror
  attn0_kernel<<<GG, 256, 0, stream>>>(
      x, batch, Wih, Whh, bih, bhh, w16f, starts, x16, q16a);

  // t = 1..5 in one kernel, 16 waves/block (4/SIMD)
  steps_kernel<<<SBLK, 1024, 0, stream>>>(
      x16, w16f, q16a, starts, bih, bhh, qstar);
}